// Round 1
// baseline (238.247 us; speedup 1.0000x reference)
//
#include <hip/hip_runtime.h>

// FocalLoss: sparse exact evaluation.
// Reference touches the full (2,4096,4096) matrix, but loss is nonzero only at
// <=2048 positive and <=32768 sampled negative positions. Set-semantics dedup
// is done exactly: candidate t (global order: pos, row-negs, col-negs)
// contributes iff no q<t has the same flat key (b*L+i)*S+j.

#define B_   2
#define L_   4096
#define S_   4096
#define P_   2048
#define N_   8
#define PN_  (P_ * N_)          // 16384
#define K_   (P_ + 2 * PN_)     // 34816 candidates total
#define TILE 4096               // keys per LDS tile (16KB)
#define CPB  64                 // candidates per block
#define NBLK (K_ / CPB)         // 544 blocks (exact)

__device__ __forceinline__ unsigned cand_key(int t,
    const int* __restrict__ b_ids, const int* __restrict__ i_ids,
    const int* __restrict__ j_ids, const int* __restrict__ rc,
    const int* __restrict__ rr) {
  if (t < P_) {
    return ((unsigned)b_ids[t] * L_ + (unsigned)i_ids[t]) * S_ + (unsigned)j_ids[t];
  } else if (t < P_ + PN_) {
    int u = t - P_;
    int p = u >> 3;                       // N_ == 8
    int col = rc[u];
    col += (col >= j_ids[p]) ? 1 : 0;     // skip the positive's column
    return ((unsigned)b_ids[p] * L_ + (unsigned)i_ids[p]) * S_ + (unsigned)col;
  } else {
    int u = t - P_ - PN_;
    int p = u >> 3;
    int row = rr[u];
    row += (row >= i_ids[p]) ? 1 : 0;     // skip the positive's row
    return ((unsigned)b_ids[p] * L_ + (unsigned)row) * S_ + (unsigned)j_ids[p];
  }
}

__global__ __launch_bounds__(256) void focal_main(
    const float* __restrict__ conf,
    const int* __restrict__ b_ids, const int* __restrict__ i_ids,
    const int* __restrict__ j_ids, const int* __restrict__ rc,
    const int* __restrict__ rr,
    float* __restrict__ partial, unsigned* __restrict__ cnts) {
  __shared__ unsigned shk[TILE];
  __shared__ float red[4];
  __shared__ unsigned redc[4];

  const int tid = threadIdx.x;
  const int c = tid >> 2;          // candidate slot within block
  const int r = tid & 3;           // 4 scan threads per candidate
  const int t = blockIdx.x * CPB + c;   // my candidate index (< K_ always)

  const unsigned myKey = cand_key(t, b_ids, i_ids, j_ids, rc, rr);

  bool excluded = false;
  const int scan_end = blockIdx.x * CPB + CPB;  // need q < t <= scan_end-1

  for (int ts = 0; ts < scan_end - 1; ts += TILE) {
    // cooperatively (re)compute this tile of keys into LDS (inputs L2-resident)
    #pragma unroll
    for (int k = 0; k < TILE / 256; ++k) {
      int g = ts + tid + k * 256;
      shk[tid + k * 256] = (g < K_) ? cand_key(g, b_ids, i_ids, j_ids, rc, rr)
                                    : 0xFFFFFFFFu;  // sentinel (> any valid key)
    }
    __syncthreads();
    // scan: thread r covers locals {j*16 + r*4 .. +3} -> conflict-free uint4 reads
    for (int j = 0; j < TILE / 16; ++j) {
      int base = j * 16 + r * 4;
      uint4 v = *reinterpret_cast<const uint4*>(&shk[base]);
      int q0 = ts + base;
      excluded |= (v.x == myKey) & (q0 + 0 < t);
      excluded |= (v.y == myKey) & (q0 + 1 < t);
      excluded |= (v.z == myKey) & (q0 + 2 < t);
      excluded |= (v.w == myKey) & (q0 + 3 < t);
    }
    __syncthreads();
  }

  // OR the 4 scan threads' flags via wave ballot (quads are 4-aligned in a wave)
  unsigned long long ball = __ballot(excluded);
  int lane = tid & 63;
  bool exc = ((ball >> (lane & ~3)) & 0xFull) != 0;

  float term = 0.0f;
  unsigned cnt = 0;
  if (r == 0 && !exc) {
    float cv = conf[myKey];                     // key IS the flat index
    float p = fminf(fmaxf(cv, 1e-7f), 1.0f - 1e-7f);
    if (t < P_) {
      float q1 = 1.0f - p;
      term = -0.25f * q1 * q1 * logf(p);        // WEIGHT_POS * loss_pos
      cnt = 1;
    } else {
      term = -0.75f * p * p * logf(1.0f - p);   // loss_neg
    }
  }

  // block reduction (deterministic tree)
  #pragma unroll
  for (int off = 32; off; off >>= 1) {
    term += __shfl_down(term, off);
    cnt  += __shfl_down(cnt, off);
  }
  int wave = tid >> 6;
  if (lane == 0) { red[wave] = term; redc[wave] = cnt; }
  __syncthreads();
  if (tid == 0) {
    partial[blockIdx.x] = red[0] + red[1] + red[2] + red[3];
    cnts[blockIdx.x]    = redc[0] + redc[1] + redc[2] + redc[3];
  }
}

__global__ __launch_bounds__(256) void focal_finalize(
    const float* __restrict__ partial, const unsigned* __restrict__ cnts,
    float* __restrict__ out) {
  __shared__ float red[4];
  __shared__ unsigned redc[4];
  int tid = threadIdx.x;
  float s = 0.0f;
  unsigned c = 0;
  for (int i = tid; i < NBLK; i += 256) { s += partial[i]; c += cnts[i]; }
  #pragma unroll
  for (int off = 32; off; off >>= 1) {
    s += __shfl_down(s, off);
    c += __shfl_down(c, off);
  }
  if ((tid & 63) == 0) { red[tid >> 6] = s; redc[tid >> 6] = c; }
  __syncthreads();
  if (tid == 0) {
    float fs = red[0] + red[1] + red[2] + red[3];
    unsigned fc = redc[0] + redc[1] + redc[2] + redc[3];
    out[0] = fs / (float)fc;
  }
}

extern "C" void kernel_launch(void* const* d_in, const int* in_sizes, int n_in,
                              void* d_out, int out_size, void* d_ws, size_t ws_size,
                              hipStream_t stream) {
  const float* conf  = (const float*)d_in[0];
  const int*   b_ids = (const int*)d_in[1];
  const int*   i_ids = (const int*)d_in[2];
  const int*   j_ids = (const int*)d_in[3];
  const int*   rc    = (const int*)d_in[4];
  const int*   rr    = (const int*)d_in[5];

  float*    partial = (float*)d_ws;              // NBLK floats
  unsigned* cnts    = (unsigned*)d_ws + NBLK;    // NBLK uints (4.4KB total)

  focal_main<<<NBLK, 256, 0, stream>>>(conf, b_ids, i_ids, j_ids, rc, rr,
                                       partial, cnts);
  focal_finalize<<<1, 256, 0, stream>>>(partial, cnts, (float*)d_out);
}

// Round 2
// 32.273 us; speedup vs baseline: 7.3822x; 7.3822x over previous
//
#include <hip/hip_runtime.h>

// FocalLoss, sparse exact evaluation via hash-table dedup.
// Loss is nonzero only at <=2048 positive + <=32768 sampled negative positions.
// Set semantics: distinct key counts once; pos beats neg (neg_mask *= 1-pos_mask).
// Since all positive candidate indices (0..P-1) precede negatives, "owner =
// min candidate index per distinct key" encodes both dedup and pos-priority.

#define B_   2
#define L_   4096
#define S_   4096
#define P_   2048
#define N_   8
#define PN_  (P_ * N_)          // 16384
#define K_   (P_ + 2 * PN_)     // 34816 candidates
#define TBITS 16
#define TSIZE (1u << TBITS)     // 65536 hash slots (load factor ~0.53)
#define TMASK (TSIZE - 1u)
#define EMPTYK 0xFFFFFFFFu      // valid keys < 2^25
#define P2BLK ((int)(TSIZE / 256))   // 256 slot-sweep blocks

// ---- shared key generator -------------------------------------------------
__device__ __forceinline__ unsigned cand_key(int t,
    const int* __restrict__ b_ids, const int* __restrict__ i_ids,
    const int* __restrict__ j_ids, const int* __restrict__ rc,
    const int* __restrict__ rr) {
  if (t < P_) {
    return ((unsigned)b_ids[t] * L_ + (unsigned)i_ids[t]) * S_ + (unsigned)j_ids[t];
  } else if (t < P_ + PN_) {
    int u = t - P_;
    int p = u >> 3;                       // N_ == 8
    int col = rc[u];
    col += (col >= j_ids[p]) ? 1 : 0;     // torch: rand[rand >= idx] += 1
    return ((unsigned)b_ids[p] * L_ + (unsigned)i_ids[p]) * S_ + (unsigned)col;
  } else {
    int u = t - P_ - PN_;
    int p = u >> 3;
    int row = rr[u];
    row += (row >= i_ids[p]) ? 1 : 0;
    return ((unsigned)b_ids[p] * L_ + (unsigned)row) * S_ + (unsigned)j_ids[p];
  }
}

__device__ __forceinline__ float focal_term(float cv, bool is_pos) {
  float p = fminf(fmaxf(cv, 1e-7f), 1.0f - 1e-7f);
  if (is_pos) { float q = 1.0f - p; return -0.25f * q * q * logf(p); }
  return -0.75f * p * p * logf(1.0f - p);
}

// ---- fast path: hash insert + slot sweep ----------------------------------
__global__ __launch_bounds__(256) void focal_insert(
    const int* __restrict__ b_ids, const int* __restrict__ i_ids,
    const int* __restrict__ j_ids, const int* __restrict__ rc,
    const int* __restrict__ rr,
    unsigned* __restrict__ keys, unsigned* __restrict__ owner) {
  int t = blockIdx.x * 256 + threadIdx.x;
  if (t >= K_) return;
  unsigned key = cand_key(t, b_ids, i_ids, j_ids, rc, rr);
  unsigned h = (key * 2654435761u) >> (32 - TBITS);
  while (true) {
    unsigned cur = keys[h];
    if (cur == key) { atomicMin(&owner[h], (unsigned)t); break; }
    if (cur == EMPTYK) {
      unsigned old = atomicCAS(&keys[h], EMPTYK, key);
      if (old == EMPTYK || old == key) { atomicMin(&owner[h], (unsigned)t); break; }
    }
    h = (h + 1) & TMASK;
  }
}

__global__ __launch_bounds__(256) void focal_slots(
    const float* __restrict__ conf,
    const unsigned* __restrict__ keys, const unsigned* __restrict__ owner,
    float* __restrict__ partial, unsigned* __restrict__ cnts) {
  __shared__ float red[4];
  __shared__ unsigned redc[4];
  int tid = threadIdx.x;
  int slot = blockIdx.x * 256 + tid;
  unsigned key = keys[slot];
  float term = 0.0f;
  unsigned cnt = 0;
  if (key != EMPTYK) {
    bool is_pos = owner[slot] < P_;
    term = focal_term(conf[key], is_pos);
    cnt = is_pos ? 1u : 0u;
  }
  #pragma unroll
  for (int off = 32; off; off >>= 1) {
    term += __shfl_down(term, off);
    cnt  += __shfl_down(cnt, off);
  }
  if ((tid & 63) == 0) { red[tid >> 6] = term; redc[tid >> 6] = cnt; }
  __syncthreads();
  if (tid == 0) {
    partial[blockIdx.x] = red[0] + red[1] + red[2] + red[3];
    cnts[blockIdx.x]    = redc[0] + redc[1] + redc[2] + redc[3];
  }
}

__global__ __launch_bounds__(256) void focal_reduce(
    const float* __restrict__ partial, const unsigned* __restrict__ cnts,
    int nblk, float* __restrict__ out) {
  __shared__ float red[4];
  __shared__ unsigned redc[4];
  int tid = threadIdx.x;
  float s = 0.0f;
  unsigned c = 0;
  for (int i = tid; i < nblk; i += 256) { s += partial[i]; c += cnts[i]; }
  #pragma unroll
  for (int off = 32; off; off >>= 1) {
    s += __shfl_down(s, off);
    c += __shfl_down(c, off);
  }
  if ((tid & 63) == 0) { red[tid >> 6] = s; redc[tid >> 6] = c; }
  __syncthreads();
  if (tid == 0) {
    float fs = red[0] + red[1] + red[2] + red[3];
    unsigned fc = redc[0] + redc[1] + redc[2] + redc[3];
    out[0] = fs / (float)fc;
  }
}

// ---- fallback path (proven round-1 O(K^2) scan, needs only ~4.4KB ws) -----
#define TILE 4096
#define CPB  64
#define NBLK (K_ / CPB)         // 544

__global__ __launch_bounds__(256) void focal_main(
    const float* __restrict__ conf,
    const int* __restrict__ b_ids, const int* __restrict__ i_ids,
    const int* __restrict__ j_ids, const int* __restrict__ rc,
    const int* __restrict__ rr,
    float* __restrict__ partial, unsigned* __restrict__ cnts) {
  __shared__ unsigned shk[TILE];
  __shared__ float red[4];
  __shared__ unsigned redc[4];

  const int tid = threadIdx.x;
  const int c = tid >> 2;
  const int r = tid & 3;
  const int t = blockIdx.x * CPB + c;

  const unsigned myKey = cand_key(t, b_ids, i_ids, j_ids, rc, rr);

  bool excluded = false;
  const int scan_end = blockIdx.x * CPB + CPB;

  for (int ts = 0; ts < scan_end - 1; ts += TILE) {
    #pragma unroll
    for (int k = 0; k < TILE / 256; ++k) {
      int g = ts + tid + k * 256;
      shk[tid + k * 256] = (g < K_) ? cand_key(g, b_ids, i_ids, j_ids, rc, rr)
                                    : 0xFFFFFFFFu;
    }
    __syncthreads();
    for (int j = 0; j < TILE / 16; ++j) {
      int base = j * 16 + r * 4;
      uint4 v = *reinterpret_cast<const uint4*>(&shk[base]);
      int q0 = ts + base;
      excluded |= (v.x == myKey) & (q0 + 0 < t);
      excluded |= (v.y == myKey) & (q0 + 1 < t);
      excluded |= (v.z == myKey) & (q0 + 2 < t);
      excluded |= (v.w == myKey) & (q0 + 3 < t);
    }
    __syncthreads();
  }

  unsigned long long ball = __ballot(excluded);
  int lane = tid & 63;
  bool exc = ((ball >> (lane & ~3)) & 0xFull) != 0;

  float term = 0.0f;
  unsigned cnt = 0;
  if (r == 0 && !exc) {
    term = focal_term(conf[myKey], t < P_);
    cnt = (t < P_) ? 1u : 0u;
  }
  #pragma unroll
  for (int off = 32; off; off >>= 1) {
    term += __shfl_down(term, off);
    cnt  += __shfl_down(cnt, off);
  }
  int wave = tid >> 6;
  if (lane == 0) { red[wave] = term; redc[wave] = cnt; }
  __syncthreads();
  if (tid == 0) {
    partial[blockIdx.x] = red[0] + red[1] + red[2] + red[3];
    cnts[blockIdx.x]    = redc[0] + redc[1] + redc[2] + redc[3];
  }
}

// ---- launch ---------------------------------------------------------------
extern "C" void kernel_launch(void* const* d_in, const int* in_sizes, int n_in,
                              void* d_out, int out_size, void* d_ws, size_t ws_size,
                              hipStream_t stream) {
  const float* conf  = (const float*)d_in[0];
  const int*   b_ids = (const int*)d_in[1];
  const int*   i_ids = (const int*)d_in[2];
  const int*   j_ids = (const int*)d_in[3];
  const int*   rc    = (const int*)d_in[4];
  const int*   rr    = (const int*)d_in[5];
  float* out = (float*)d_out;

  const size_t table_bytes = (size_t)TSIZE * 2u * sizeof(unsigned);   // keys+owner, 512KB
  const size_t need = table_bytes + (size_t)P2BLK * (sizeof(float) + sizeof(unsigned));

  if (ws_size >= need) {
    unsigned* keys  = (unsigned*)d_ws;
    unsigned* owner = keys + TSIZE;
    float*    partial = (float*)(owner + TSIZE);
    unsigned* cnts    = (unsigned*)(partial + P2BLK);

    hipMemsetAsync(d_ws, 0xFF, table_bytes, stream);   // keys=EMPTY, owner=UINT_MAX
    focal_insert<<<(K_ + 255) / 256, 256, 0, stream>>>(b_ids, i_ids, j_ids, rc, rr,
                                                       keys, owner);
    focal_slots<<<P2BLK, 256, 0, stream>>>(conf, keys, owner, partial, cnts);
    focal_reduce<<<1, 256, 0, stream>>>(partial, cnts, P2BLK, out);
  } else {
    float*    partial = (float*)d_ws;            // NBLK floats
    unsigned* cnts    = (unsigned*)d_ws + NBLK;  // NBLK uints
    focal_main<<<NBLK, 256, 0, stream>>>(conf, b_ids, i_ids, j_ids, rc, rr,
                                         partial, cnts);
    focal_reduce<<<1, 256, 0, stream>>>(partial, cnts, NBLK, out);
  }
}